// Round 4
// baseline (343.235 us; speedup 1.0000x reference)
//
#include <hip/hip_runtime.h>
#include <hip/hip_bf16.h>
#include <math.h>

#define EPSN 1e-12f
#define SSIM_C1 6.5025f     // (0.01*255)^2
#define SSIM_C2 58.5225f    // (0.03*255)^2

// Pipeline notes:
//  - Normalization a=(x+eps)/(m+eps)*255 == s*x + t with t ~ 4e-10 (negligible
//    vs values ~255 and C1=6.5). Whole pyramid kept RAW; s^2 applied in each
//    ssim epilogue (every SSIM term is quadratic in the inputs).
//  - Separable 5x5 Gaussian: per-thread rolling ring of 5 h-conv moments.
//  - 2x2 avg-pool producing the next level fused into each ssim kernel.
//  - TH=32 tiles: LDS ~19.6KB (D=1) -> 8 blocks/CU capacity (was 37KB -> 4).
//  - Staging: aligned float4 interior + scalar halo (was scalar everything).

// ---------------- ws header: [0]=maxbits (uint), [4..9)=sums[5] ----------------

__global__ void init_ws_kernel(float* ws) {
    if (threadIdx.x < 16) ws[threadIdx.x] = 0.0f;
}

// ---------------- global max of img2 (all values >= 0) ----------------

__global__ void max_kernel(const float4* __restrict__ img2, int n4,
                           unsigned* __restrict__ maxbits) {
    float m = 0.0f;
    for (int i = blockIdx.x * blockDim.x + threadIdx.x; i < n4;
         i += gridDim.x * blockDim.x) {
        float4 v = img2[i];
        m = fmaxf(fmaxf(m, fmaxf(v.x, v.y)), fmaxf(v.z, v.w));
    }
#pragma unroll
    for (int o = 32; o > 0; o >>= 1) m = fmaxf(m, __shfl_down(m, o));
    __shared__ float sm[4];
    int tid = threadIdx.x;
    if ((tid & 63) == 0) sm[tid >> 6] = m;
    __syncthreads();
    if (tid == 0) {
        float mm = fmaxf(fmaxf(sm[0], sm[1]), fmaxf(sm[2], sm[3]));
        atomicMax(maxbits, __float_as_uint(mm));
    }
}

// ---------------- separable SSIM, D<=3, tile 64x32, block (64,4) ----------------
// Thread (tx,ty): column tx, 8 outputs in y. Rolling ring of h-conv moments.

template <int D>
__global__ __launch_bounds__(256) void ssim_sep_kernel(
        const float* __restrict__ A, const float* __restrict__ B,
        int H, int W, const unsigned* __restrict__ maxbits,
        const float* __restrict__ window, float* __restrict__ sumOut,
        float* __restrict__ poolA, float* __restrict__ poolB) {
    constexpr int TW = 64, TH = 32, TPT = 8;
    constexpr int LW = TW + 4 * D, LH = TH + 4 * D, P = 4 * D + 1;
    __shared__ float2 AB[LH][LW];

    int tx = threadIdx.x, ty = threadIdx.y;
    int tid = ty * 64 + tx;
    int b = blockIdx.z;
    int x0i = blockIdx.x * TW;          // interior start (16B aligned)
    int y0 = blockIdx.y * TH - 2 * D;

    const float* Ab = A + (size_t)b * H * W;
    const float* Bb = B + (size_t)b * H * W;

    // interior staging: LH rows x 16 float4 per array (aligned)
    for (int idx = tid; idx < LH * 16; idx += 256) {
        int ly = idx >> 4, j = idx & 15;
        int gy = y0 + ly;
        float4 a = make_float4(0, 0, 0, 0), v = make_float4(0, 0, 0, 0);
        if ((unsigned)gy < (unsigned)H) {
            const float4* Ar = (const float4*)(Ab + (size_t)gy * W + x0i);
            const float4* Br = (const float4*)(Bb + (size_t)gy * W + x0i);
            a = Ar[j];
            v = Br[j];
        }
        float4* dst = (float4*)&AB[ly][2 * D + 4 * j];  // 16B aligned for D<=3
        dst[0] = make_float4(a.x, v.x, a.y, v.y);
        dst[1] = make_float4(a.z, v.z, a.w, v.w);
    }
    // halo columns: 2D left + 2D right per row
    for (int idx = tid; idx < LH * 4 * D; idx += 256) {
        int ly = idx / (4 * D), h = idx % (4 * D);
        int lx = (h < 2 * D) ? h : h + TW;
        int gx = x0i - 2 * D + lx;
        int gy = y0 + ly;
        float va = 0.0f, vb = 0.0f;
        if ((unsigned)gx < (unsigned)W && (unsigned)gy < (unsigned)H) {
            size_t g = (size_t)gy * W + gx;
            va = Ab[g];
            vb = Bb[g];
        }
        AB[ly][lx] = make_float2(va, vb);
    }
    __syncthreads();

    // fused 2x2 avg-pool of interior (raw units): 32x16 outputs
    if (poolA) {
        int pW = W >> 1;
        for (int idx = tid; idx < 32 * 16; idx += 256) {
            int py = idx >> 5, px = idx & 31;
            float2 v00 = AB[2 * D + 2 * py][2 * D + 2 * px];
            float2 v01 = AB[2 * D + 2 * py][2 * D + 2 * px + 1];
            float2 v10 = AB[2 * D + 2 * py + 1][2 * D + 2 * px];
            float2 v11 = AB[2 * D + 2 * py + 1][2 * D + 2 * px + 1];
            int gx = (x0i >> 1) + px;
            int gy = (blockIdx.y * TH >> 1) + py;
            size_t o = (size_t)b * (H >> 1) * pW + (size_t)gy * pW + gx;
            poolA[o] = 0.25f * ((v00.x + v01.x) + (v10.x + v11.x));
            poolB[o] = 0.25f * ((v00.y + v01.y) + (v10.y + v11.y));
        }
    }

    // 1-D gaussian from window row sums
    float g1[5];
#pragma unroll
    for (int k = 0; k < 5; k++)
        g1[k] = ((window[k * 5 + 0] + window[k * 5 + 1]) +
                 (window[k * 5 + 2] + window[k * 5 + 3])) + window[k * 5 + 4];

    float m = __uint_as_float(*maxbits);
    float sc = 255.0f / (m + EPSN);
    float s2 = sc * sc;
    float s2x2 = 2.0f * s2;

    float hA[P], hB[P], hAA[P], hBB[P], hAB[P];
    float local = 0.0f;
    int base = ty * TPT;

#pragma unroll
    for (int r = 0; r < TPT + 4 * D; ++r) {
        int l = base + r;
        float ha = 0, hb = 0, haa = 0, hbb = 0, hab = 0;
#pragma unroll
        for (int k = 0; k < 5; k++) {
            float2 ab = AB[l][tx + k * D];
            float w = g1[k];
            float wa = w * ab.x, wb = w * ab.y;
            ha += wa;
            hb += wb;
            haa = fmaf(wa, ab.x, haa);
            hbb = fmaf(wb, ab.y, hbb);
            hab = fmaf(wa, ab.y, hab);
        }
        int slot = r % P;
        hA[slot] = ha; hB[slot] = hb;
        hAA[slot] = haa; hBB[slot] = hbb; hAB[slot] = hab;

        if (r >= 4 * D) {
            int o = r - 4 * D;
            float m1 = 0, m2 = 0, S11 = 0, S22 = 0, S12 = 0;
#pragma unroll
            for (int k = 0; k < 5; k++) {
                int sl = (o + k * D) % P;   // compile-time after unroll
                float w = g1[k];
                m1 = fmaf(w, hA[sl], m1);
                m2 = fmaf(w, hB[sl], m2);
                S11 = fmaf(w, hAA[sl], S11);
                S22 = fmaf(w, hBB[sl], S22);
                S12 = fmaf(w, hAB[sl], S12);
            }
            float m1s = m1 * m1, m2s = m2 * m2, m12 = m1 * m2;
            float num1 = fmaf(s2x2, m12, SSIM_C1);
            float den1 = fmaf(s2, m1s + m2s, SSIM_C1);
            float num2 = fmaf(s2x2, S12 - m12, SSIM_C2);
            float den2 = fmaf(s2, (S11 - m1s) + (S22 - m2s), SSIM_C2);
            local += (num1 * num2) * __builtin_amdgcn_rcpf(den1 * den2);
        }
    }

#pragma unroll
    for (int o = 32; o > 0; o >>= 1) local += __shfl_down(local, o);
    __shared__ float part[4];
    if ((tid & 63) == 0) part[tid >> 6] = local;
    __syncthreads();
    if (tid == 0) atomicAdd(sumOut, (part[0] + part[1]) + (part[2] + part[3]));
}

// ---------------- direct SSIM for large dilation, tile 64xTH ----------------

template <int D, int TH>
__global__ __launch_bounds__(256) void ssim_direct_kernel(
        const float* __restrict__ A, const float* __restrict__ B,
        int H, int W, const unsigned* __restrict__ maxbits,
        const float* __restrict__ window, float* __restrict__ sumOut,
        float* __restrict__ poolA, float* __restrict__ poolB) {
    constexpr int TW = 64;
    constexpr int LW = TW + 4 * D, LH = TH + 4 * D, OPT = TH / 4;
    __shared__ float ldsA[LH][LW];
    __shared__ float ldsB[LH][LW];

    int tx = threadIdx.x, ty = threadIdx.y;
    int tid = ty * 64 + tx;
    int b = blockIdx.z;
    int x0i = blockIdx.x * TW;
    int y0 = blockIdx.y * TH - 2 * D;

    const float* Ab = A + (size_t)b * H * W;
    const float* Bb = B + (size_t)b * H * W;

    // interior staging (aligned float4 loads; 8B-aligned LDS writes)
    for (int idx = tid; idx < LH * 16; idx += 256) {
        int ly = idx >> 4, j = idx & 15;
        int gy = y0 + ly;
        float4 a = make_float4(0, 0, 0, 0), v = make_float4(0, 0, 0, 0);
        if ((unsigned)gy < (unsigned)H) {
            const float4* Ar = (const float4*)(Ab + (size_t)gy * W + x0i);
            const float4* Br = (const float4*)(Bb + (size_t)gy * W + x0i);
            a = Ar[j];
            v = Br[j];
        }
        float2* da = (float2*)&ldsA[ly][2 * D + 4 * j];
        float2* db = (float2*)&ldsB[ly][2 * D + 4 * j];
        da[0] = make_float2(a.x, a.y);
        da[1] = make_float2(a.z, a.w);
        db[0] = make_float2(v.x, v.y);
        db[1] = make_float2(v.z, v.w);
    }
    for (int idx = tid; idx < LH * 4 * D; idx += 256) {
        int ly = idx / (4 * D), h = idx % (4 * D);
        int lx = (h < 2 * D) ? h : h + TW;
        int gx = x0i - 2 * D + lx;
        int gy = y0 + ly;
        float va = 0.0f, vb = 0.0f;
        if ((unsigned)gx < (unsigned)W && (unsigned)gy < (unsigned)H) {
            size_t g = (size_t)gy * W + gx;
            va = Ab[g];
            vb = Bb[g];
        }
        ldsA[ly][lx] = va;
        ldsB[ly][lx] = vb;
    }
    __syncthreads();

    if (poolA) {
        int pW = W >> 1;
        for (int idx = tid; idx < 32 * (TH / 2); idx += 256) {
            int py = idx >> 5, px = idx & 31;
            float a00 = ldsA[2 * D + 2 * py][2 * D + 2 * px];
            float a01 = ldsA[2 * D + 2 * py][2 * D + 2 * px + 1];
            float a10 = ldsA[2 * D + 2 * py + 1][2 * D + 2 * px];
            float a11 = ldsA[2 * D + 2 * py + 1][2 * D + 2 * px + 1];
            float b00 = ldsB[2 * D + 2 * py][2 * D + 2 * px];
            float b01 = ldsB[2 * D + 2 * py][2 * D + 2 * px + 1];
            float b10 = ldsB[2 * D + 2 * py + 1][2 * D + 2 * px];
            float b11 = ldsB[2 * D + 2 * py + 1][2 * D + 2 * px + 1];
            int gx = (x0i >> 1) + px;
            int gy = (blockIdx.y * TH >> 1) + py;
            size_t o = (size_t)b * (H >> 1) * pW + (size_t)gy * pW + gx;
            poolA[o] = 0.25f * ((a00 + a01) + (a10 + a11));
            poolB[o] = 0.25f * ((b00 + b01) + (b10 + b11));
        }
    }

    float wv[25];
#pragma unroll
    for (int i = 0; i < 25; i++) wv[i] = window[i];

    float m = __uint_as_float(*maxbits);
    float sc = 255.0f / (m + EPSN);
    float s2 = sc * sc;
    float s2x2 = 2.0f * s2;

    float mu1[OPT] = {}, mu2[OPT] = {};
    float s11[OPT] = {}, s22[OPT] = {}, s12[OPT] = {};
    int ry = ty * OPT;
#pragma unroll
    for (int ky = 0; ky < 5; ky++) {
#pragma unroll
        for (int kx = 0; kx < 5; kx++) {
            float w = wv[ky * 5 + kx];
#pragma unroll
            for (int j = 0; j < OPT; j++) {
                float a = ldsA[ry + j + ky * D][tx + kx * D];
                float bb = ldsB[ry + j + ky * D][tx + kx * D];
                float wa = w * a, wb = w * bb;
                mu1[j] += wa;
                mu2[j] += wb;
                s11[j] = fmaf(wa, a, s11[j]);
                s22[j] = fmaf(wb, bb, s22[j]);
                s12[j] = fmaf(wa, bb, s12[j]);
            }
        }
    }

    float local = 0.0f;
#pragma unroll
    for (int j = 0; j < OPT; j++) {
        float m1s = mu1[j] * mu1[j], m2s = mu2[j] * mu2[j], m12 = mu1[j] * mu2[j];
        float num1 = fmaf(s2x2, m12, SSIM_C1);
        float den1 = fmaf(s2, m1s + m2s, SSIM_C1);
        float num2 = fmaf(s2x2, s12[j] - m12, SSIM_C2);
        float den2 = fmaf(s2, (s11[j] - m1s) + (s22[j] - m2s), SSIM_C2);
        local += (num1 * num2) * __builtin_amdgcn_rcpf(den1 * den2);
    }

#pragma unroll
    for (int o = 32; o > 0; o >>= 1) local += __shfl_down(local, o);
    __shared__ float part[4];
    if ((tid & 63) == 0) part[tid >> 6] = local;
    __syncthreads();
    if (tid == 0) atomicAdd(sumOut, (part[0] + part[1]) + (part[2] + part[3]));
}

// ---------------- finalize ----------------

__global__ void final_kernel(const float* __restrict__ sums,
                             const float* __restrict__ weights,
                             unsigned* __restrict__ out) {
    if (blockIdx.x == 0 && threadIdx.x == 0) {
        const float counts[5] = {16.0f * 1024 * 1024, 16.0f * 512 * 512,
                                 16.0f * 256 * 256,   16.0f * 128 * 128,
                                 16.0f * 64 * 64};
        float prod = 1.0f;
#pragma unroll
        for (int i = 0; i < 5; i++) {
            float m = sums[i] / counts[i];
            prod *= powf(m, weights[i]);
        }
        float r = 1.0f - prod;
        unsigned bits = __float_as_uint(r);
        unsigned lsb = (bits >> 16) & 1u;
        unsigned hi = (bits + 0x7FFFu + lsb) >> 16;
        out[0] = (hi << 16) | hi;
    }
}

// ---------------- host launch ----------------

extern "C" void kernel_launch(void* const* d_in, const int* in_sizes, int n_in,
                              void* d_out, int out_size, void* d_ws, size_t ws_size,
                              hipStream_t stream) {
    const float* img1 = (const float*)d_in[0];
    const float* img2 = (const float*)d_in[1];
    const float* window = (const float*)d_in[2];
    const float* weights = (const float*)d_in[3];

    float* ws = (float*)d_ws;
    unsigned* maxbits = (unsigned*)d_ws;
    float* sums = ws + 4;
    size_t off = 16;
    float* a1 = ws + off; off += (size_t)16 * 512 * 512;
    float* b1 = ws + off; off += (size_t)16 * 512 * 512;
    float* a2 = ws + off; off += (size_t)16 * 256 * 256;
    float* b2 = ws + off; off += (size_t)16 * 256 * 256;
    float* a3 = ws + off; off += (size_t)16 * 128 * 128;
    float* b3 = ws + off; off += (size_t)16 * 128 * 128;
    float* a4 = ws + off; off += (size_t)16 * 64 * 64;
    float* b4 = ws + off; off += (size_t)16 * 64 * 64;

    dim3 blk(64, 4, 1);

    init_ws_kernel<<<1, 64, 0, stream>>>(ws);
    max_kernel<<<2048, 256, 0, stream>>>((const float4*)img2,
                                         16 * 1024 * 1024 / 4, maxbits);

    // level 0: ssim + fused pool -> (a1,b1)
    ssim_sep_kernel<1><<<dim3(16, 32, 16), blk, 0, stream>>>(
        img1, img2, 1024, 1024, maxbits, window, sums + 0, a1, b1);
    // level 1
    ssim_sep_kernel<2><<<dim3(8, 16, 16), blk, 0, stream>>>(
        a1, b1, 512, 512, maxbits, window, sums + 1, a2, b2);
    // level 2
    ssim_sep_kernel<3><<<dim3(4, 8, 16), blk, 0, stream>>>(
        a2, b2, 256, 256, maxbits, window, sums + 2, a3, b3);
    // level 3 (direct, D=6, TH=8), pool -> (a4,b4)
    ssim_direct_kernel<6, 8><<<dim3(2, 16, 16), blk, 0, stream>>>(
        a3, b3, 128, 128, maxbits, window, sums + 3, a4, b4);
    // level 4 (direct, D=9, TH=8), no pool
    ssim_direct_kernel<9, 8><<<dim3(1, 8, 16), blk, 0, stream>>>(
        a4, b4, 64, 64, maxbits, window, sums + 4, nullptr, nullptr);

    final_kernel<<<1, 64, 0, stream>>>(sums, weights, (unsigned*)d_out);
}

// Round 5
// 302.935 us; speedup vs baseline: 1.1330x; 1.1330x over previous
//
#include <hip/hip_runtime.h>
#include <math.h>

#define EPSN 1e-12f
#define SSIM_C1 6.5025f     // (0.01*255)^2
#define SSIM_C2 58.5225f    // (0.03*255)^2

// Pipeline notes:
//  - Normalization (x+eps)/(m+eps)*255 = s*x + t, t~4e-10 negligible -> drop t,
//    keep pyramid RAW-scaled, fold s^2 into each epilogue (all terms quadratic).
//  - (P,M)=(A+B,A-B) basis: epilogue needs only p=conv(P), m=conv(M),
//    PP=conv(P^2), MM=conv(M^2):  mu1*mu2=(p^2-m^2)/4, mu1^2+mu2^2=(p^2+m^2)/2,
//    S11+S22=(PP+MM)/2, S12=(PP-MM)/4.  4 conv fields instead of 5, and P,M
//    are linear in A,B so avg-pool pyramid lives in (P,M) space.
//  - vf2 (ext_vector float2) math so P/M pairs can map to v_pk_* ops.
//  - Separable 5x5 Gaussian; per-thread ring of 5 h-conv moment pairs, with
//    phase-major iteration so the ring is 5 deep for every dilation.
//  - Level-0 staging float4 + sigma-swizzle (conflict-free b128 writes);
//    levels>=1 stage from interleaved (P,M) arrays with consecutive chunks.

typedef __attribute__((ext_vector_type(2))) float vf2;

__global__ void init_ws_kernel(float* ws) {
    if (threadIdx.x < 16) ws[threadIdx.x] = 0.0f;
}

__global__ void max_kernel(const float4* __restrict__ img2, int n4,
                           unsigned* __restrict__ maxbits) {
    float m = 0.0f;
    for (int i = blockIdx.x * blockDim.x + threadIdx.x; i < n4;
         i += gridDim.x * blockDim.x) {
        float4 v = img2[i];
        m = fmaxf(fmaxf(m, fmaxf(v.x, v.y)), fmaxf(v.z, v.w));
    }
#pragma unroll
    for (int o = 32; o > 0; o >>= 1) m = fmaxf(m, __shfl_down(m, o));
    __shared__ float sm[4];
    int tid = threadIdx.x;
    if ((tid & 63) == 0) sm[tid >> 6] = m;
    __syncthreads();
    if (tid == 0) {
        float mm = fmaxf(fmaxf(sm[0], sm[1]), fmaxf(sm[2], sm[3]));
        atomicMax(maxbits, __float_as_uint(mm));
    }
}

// ---------------- separable SSIM, tile 64x64, block (64,4), TPT=16 ----------------

template <int D, bool RAW>
__global__ __launch_bounds__(256) void ssim_sep_kernel(
        const float* __restrict__ A, const float* __restrict__ B,
        int H, int W, const unsigned* __restrict__ maxbits,
        const float* __restrict__ window, float* __restrict__ sumOut,
        vf2* __restrict__ poolPM) {
    constexpr int TW = 64, TH = 64, TPT = 16;
    constexpr int LW = TW + 4 * D, LH = TH + 4 * D;
    __shared__ vf2 AB[LH][LW];

    int tx = threadIdx.x, ty = threadIdx.y;
    int tid = ty * 64 + tx;
    int b = blockIdx.z;
    int x0i = blockIdx.x * TW;           // interior start (element/pair units)
    int y0 = blockIdx.y * TH - 2 * D;

    if (RAW) {
        const float* Ab = A + (size_t)b * H * W;
        const float* Bb = B + (size_t)b * H * W;
        // interior: 16 float4 per row per plane; sigma-swizzled chunk writes
        for (int idx = tid; idx < LH * 16; idx += 256) {
            int ly = idx >> 4, j = idx & 15;
            int gy = y0 + ly;
            float4 a = make_float4(0, 0, 0, 0), v = make_float4(0, 0, 0, 0);
            if ((unsigned)gy < (unsigned)H) {
                a = *(const float4*)(Ab + (size_t)gy * W + x0i + 4 * j);
                v = *(const float4*)(Bb + (size_t)gy * W + x0i + 4 * j);
            }
            float4 lo = make_float4(a.x + v.x, a.x - v.x, a.y + v.y, a.y - v.y);
            float4 hi = make_float4(a.z + v.z, a.z - v.z, a.w + v.w, a.w - v.w);
            int sig = ((j >> 2) ^ j) & 1;
            float4* rowp = (float4*)(&AB[ly][0]);
            rowp[D + 2 * j + sig] = sig ? hi : lo;
            rowp[D + 2 * j + 1 - sig] = sig ? lo : hi;
        }
        for (int idx = tid; idx < LH * 4 * D; idx += 256) {
            int ly = idx / (4 * D), h = idx % (4 * D);
            int lx = (h < 2 * D) ? h : h + TW;
            int gx = x0i - 2 * D + lx;
            int gy = y0 + ly;
            vf2 pm = {0.0f, 0.0f};
            if ((unsigned)gx < (unsigned)W && (unsigned)gy < (unsigned)H) {
                size_t g = (size_t)gy * W + gx;
                float a = Ab[g], v = Bb[g];
                pm = vf2{a + v, a - v};
            }
            AB[ly][lx] = pm;
        }
    } else {
        const vf2* pmIn = (const vf2*)A;
        const vf2* base = pmIn + (size_t)b * H * W;
        for (int idx = tid; idx < LH * 32; idx += 256) {
            int ly = idx >> 5, j = idx & 31;
            int gy = y0 + ly;
            float4 g = make_float4(0, 0, 0, 0);
            if ((unsigned)gy < (unsigned)H)
                g = *(const float4*)(base + (size_t)gy * W + x0i + 2 * j);
            ((float4*)&AB[ly][0])[D + j] = g;  // consecutive chunks: conflict-free
        }
        for (int idx = tid; idx < LH * 4 * D; idx += 256) {
            int ly = idx / (4 * D), h = idx % (4 * D);
            int lx = (h < 2 * D) ? h : h + TW;
            int gx = x0i - 2 * D + lx;
            int gy = y0 + ly;
            vf2 pm = {0.0f, 0.0f};
            if ((unsigned)gx < (unsigned)W && (unsigned)gy < (unsigned)H)
                pm = base[(size_t)gy * W + gx];
            AB[ly][lx] = pm;
        }
    }
    __syncthreads();

    // fused 2x2 avg-pool of interior (P,M linear -> pool directly)
    if (poolPM) {
        int pW = W >> 1;
        for (int idx = tid; idx < 32 * 16; idx += 256) {
            int py = idx >> 4, j2 = idx & 15;   // j2 indexes 2 pooled pairs
            int sx = 2 * D + 4 * j2, sy = 2 * D + 2 * py;
            vf2 s00 = AB[sy][sx],     s01 = AB[sy][sx + 1];
            vf2 s10 = AB[sy + 1][sx], s11 = AB[sy + 1][sx + 1];
            vf2 o0 = 0.25f * ((s00 + s01) + (s10 + s11));
            vf2 t00 = AB[sy][sx + 2],     t01 = AB[sy][sx + 3];
            vf2 t10 = AB[sy + 1][sx + 2], t11 = AB[sy + 1][sx + 3];
            vf2 o1 = 0.25f * ((t00 + t01) + (t10 + t11));
            int gx = (x0i >> 1) + 2 * j2;
            int gy = ((blockIdx.y * TH) >> 1) + py;
            float4 o = make_float4(o0.x, o0.y, o1.x, o1.y);
            *(float4*)(poolPM + (size_t)b * (H >> 1) * pW + (size_t)gy * pW + gx) = o;
        }
    }

    float g1[5];
#pragma unroll
    for (int k = 0; k < 5; k++)
        g1[k] = ((window[k * 5 + 0] + window[k * 5 + 1]) +
                 (window[k * 5 + 2] + window[k * 5 + 3])) + window[k * 5 + 4];

    float mx = __uint_as_float(*maxbits);
    float sc = 255.0f / (mx + EPSN);
    float s2h = 0.5f * sc * sc;

    vf2 rPM[5], rSQ[5];
    float local = 0.0f;
    int rbase = ty * TPT;

#pragma unroll
    for (int ph = 0; ph < D; ++ph) {
        const int cnt = (TPT - ph + D - 1) / D;   // outputs in this phase
#pragma unroll
        for (int k = 0; k < cnt + 4; ++k) {
            int l = rbase + ph + k * D;
            vf2 hpm = {0.0f, 0.0f}, hsq = {0.0f, 0.0f};
#pragma unroll
            for (int kt = 0; kt < 5; kt++) {
                vf2 ab = AB[l][tx + kt * D];
                vf2 wab = g1[kt] * ab;
                hpm += wab;
                hsq += wab * ab;   // contracts to (pk) fma
            }
            rPM[k % 5] = hpm;
            rSQ[k % 5] = hsq;
            if (k >= 4) {
                vf2 vpm = {0.0f, 0.0f}, vsq = {0.0f, 0.0f};
#pragma unroll
                for (int kt = 0; kt < 5; kt++) {
                    int sl = (k - 4 + kt) % 5;   // compile-time after unroll
                    vpm += g1[kt] * rPM[sl];
                    vsq += g1[kt] * rSQ[sl];
                }
                float u = vpm.x * vpm.x, vv = vpm.y * vpm.y;
                float upv = u + vv, umv = u - vv;
                float qp = vsq.x + vsq.y, qm = vsq.x - vsq.y;
                float num1 = fmaf(s2h, umv, SSIM_C1);
                float den1 = fmaf(s2h, upv, SSIM_C1);
                float num2 = fmaf(s2h, qm - umv, SSIM_C2);
                float den2 = fmaf(s2h, qp - upv, SSIM_C2);
                local += (num1 * num2) * __builtin_amdgcn_rcpf(den1 * den2);
            }
        }
    }

#pragma unroll
    for (int o = 32; o > 0; o >>= 1) local += __shfl_down(local, o);
    __shared__ float part[4];
    if ((tid & 63) == 0) part[tid >> 6] = local;
    __syncthreads();
    if (tid == 0) atomicAdd(sumOut, (part[0] + part[1]) + (part[2] + part[3]));
}

// ---------------- direct SSIM for large dilation, interleaved (P,M) input ----------------

template <int D, int TH>
__global__ __launch_bounds__(256) void ssim_direct_kernel(
        const vf2* __restrict__ pmIn, int H, int W,
        const unsigned* __restrict__ maxbits,
        const float* __restrict__ window, float* __restrict__ sumOut,
        vf2* __restrict__ poolPM) {
    constexpr int TW = 64;
    constexpr int LW = TW + 4 * D, LH = TH + 4 * D, OPT = TH / 4;
    __shared__ vf2 AB[LH][LW];

    int tx = threadIdx.x, ty = threadIdx.y;
    int tid = ty * 64 + tx;
    int b = blockIdx.z;
    int x0i = blockIdx.x * TW;
    int y0 = blockIdx.y * TH - 2 * D;
    const vf2* base = pmIn + (size_t)b * H * W;

    for (int idx = tid; idx < LH * 32; idx += 256) {
        int ly = idx >> 5, j = idx & 31;
        int gy = y0 + ly;
        float4 g = make_float4(0, 0, 0, 0);
        if ((unsigned)gy < (unsigned)H)
            g = *(const float4*)(base + (size_t)gy * W + x0i + 2 * j);
        ((float4*)&AB[ly][0])[D + j] = g;
    }
    for (int idx = tid; idx < LH * 4 * D; idx += 256) {
        int ly = idx / (4 * D), h = idx % (4 * D);
        int lx = (h < 2 * D) ? h : h + TW;
        int gx = x0i - 2 * D + lx;
        int gy = y0 + ly;
        vf2 pm = {0.0f, 0.0f};
        if ((unsigned)gx < (unsigned)W && (unsigned)gy < (unsigned)H)
            pm = base[(size_t)gy * W + gx];
        AB[ly][lx] = pm;
    }
    __syncthreads();

    if (poolPM) {
        int pW = W >> 1;
        for (int idx = tid; idx < 16 * (TH / 2); idx += 256) {
            int py = idx >> 4, j2 = idx & 15;
            int sx = 2 * D + 4 * j2, sy = 2 * D + 2 * py;
            vf2 s00 = AB[sy][sx],     s01 = AB[sy][sx + 1];
            vf2 s10 = AB[sy + 1][sx], s11 = AB[sy + 1][sx + 1];
            vf2 o0 = 0.25f * ((s00 + s01) + (s10 + s11));
            vf2 t00 = AB[sy][sx + 2],     t01 = AB[sy][sx + 3];
            vf2 t10 = AB[sy + 1][sx + 2], t11 = AB[sy + 1][sx + 3];
            vf2 o1 = 0.25f * ((t00 + t01) + (t10 + t11));
            int gx = (x0i >> 1) + 2 * j2;
            int gy = ((blockIdx.y * TH) >> 1) + py;
            float4 o = make_float4(o0.x, o0.y, o1.x, o1.y);
            *(float4*)(poolPM + (size_t)b * (H >> 1) * pW + (size_t)gy * pW + gx) = o;
        }
    }

    float wv[25];
#pragma unroll
    for (int i = 0; i < 25; i++) wv[i] = window[i];

    float mx = __uint_as_float(*maxbits);
    float sc = 255.0f / (mx + EPSN);
    float s2h = 0.5f * sc * sc;

    vf2 mu[OPT], sq[OPT];
#pragma unroll
    for (int j = 0; j < OPT; j++) { mu[j] = vf2{0, 0}; sq[j] = vf2{0, 0}; }
    int ry = ty * OPT;
#pragma unroll
    for (int ky = 0; ky < 5; ky++) {
#pragma unroll
        for (int kx = 0; kx < 5; kx++) {
            float w = wv[ky * 5 + kx];
#pragma unroll
            for (int j = 0; j < OPT; j++) {
                vf2 ab = AB[ry + j + ky * D][tx + kx * D];
                vf2 wab = w * ab;
                mu[j] += wab;
                sq[j] += wab * ab;
            }
        }
    }

    float local = 0.0f;
#pragma unroll
    for (int j = 0; j < OPT; j++) {
        float u = mu[j].x * mu[j].x, vv = mu[j].y * mu[j].y;
        float upv = u + vv, umv = u - vv;
        float qp = sq[j].x + sq[j].y, qm = sq[j].x - sq[j].y;
        float num1 = fmaf(s2h, umv, SSIM_C1);
        float den1 = fmaf(s2h, upv, SSIM_C1);
        float num2 = fmaf(s2h, qm - umv, SSIM_C2);
        float den2 = fmaf(s2h, qp - upv, SSIM_C2);
        local += (num1 * num2) * __builtin_amdgcn_rcpf(den1 * den2);
    }

#pragma unroll
    for (int o = 32; o > 0; o >>= 1) local += __shfl_down(local, o);
    __shared__ float part[4];
    if ((tid & 63) == 0) part[tid >> 6] = local;
    __syncthreads();
    if (tid == 0) atomicAdd(sumOut, (part[0] + part[1]) + (part[2] + part[3]));
}

// ---------------- finalize ----------------

__global__ void final_kernel(const float* __restrict__ sums,
                             const float* __restrict__ weights,
                             unsigned* __restrict__ out) {
    if (blockIdx.x == 0 && threadIdx.x == 0) {
        const float counts[5] = {16.0f * 1024 * 1024, 16.0f * 512 * 512,
                                 16.0f * 256 * 256,   16.0f * 128 * 128,
                                 16.0f * 64 * 64};
        float prod = 1.0f;
#pragma unroll
        for (int i = 0; i < 5; i++) {
            float m = sums[i] / counts[i];
            prod *= powf(m, weights[i]);
        }
        float r = 1.0f - prod;
        unsigned bits = __float_as_uint(r);
        unsigned lsb = (bits >> 16) & 1u;
        unsigned hi = (bits + 0x7FFFu + lsb) >> 16;
        out[0] = (hi << 16) | hi;
    }
}

// ---------------- host launch ----------------

extern "C" void kernel_launch(void* const* d_in, const int* in_sizes, int n_in,
                              void* d_out, int out_size, void* d_ws, size_t ws_size,
                              hipStream_t stream) {
    const float* img1 = (const float*)d_in[0];
    const float* img2 = (const float*)d_in[1];
    const float* window = (const float*)d_in[2];
    const float* weights = (const float*)d_in[3];

    float* ws = (float*)d_ws;
    unsigned* maxbits = (unsigned*)d_ws;
    float* sums = ws + 4;
    size_t off = 16;
    vf2* pm1 = (vf2*)(ws + off); off += (size_t)16 * 512 * 512 * 2;
    vf2* pm2 = (vf2*)(ws + off); off += (size_t)16 * 256 * 256 * 2;
    vf2* pm3 = (vf2*)(ws + off); off += (size_t)16 * 128 * 128 * 2;
    vf2* pm4 = (vf2*)(ws + off); off += (size_t)16 * 64 * 64 * 2;

    dim3 blk(64, 4, 1);

    init_ws_kernel<<<1, 64, 0, stream>>>(ws);
    max_kernel<<<2048, 256, 0, stream>>>((const float4*)img2,
                                         16 * 1024 * 1024 / 4, maxbits);

    ssim_sep_kernel<1, true><<<dim3(16, 16, 16), blk, 0, stream>>>(
        img1, img2, 1024, 1024, maxbits, window, sums + 0, pm1);
    ssim_sep_kernel<2, false><<<dim3(8, 8, 16), blk, 0, stream>>>(
        (const float*)pm1, nullptr, 512, 512, maxbits, window, sums + 1, pm2);
    ssim_sep_kernel<3, false><<<dim3(4, 4, 16), blk, 0, stream>>>(
        (const float*)pm2, nullptr, 256, 256, maxbits, window, sums + 2, pm3);
    ssim_direct_kernel<6, 8><<<dim3(2, 16, 16), blk, 0, stream>>>(
        pm3, 128, 128, maxbits, window, sums + 3, pm4);
    ssim_direct_kernel<9, 8><<<dim3(1, 8, 16), blk, 0, stream>>>(
        pm4, 64, 64, maxbits, window, sums + 4, nullptr);

    final_kernel<<<1, 64, 0, stream>>>(sums, weights, (unsigned*)d_out);
}